// Round 1
// baseline (1607.205 us; speedup 1.0000x reference)
//
#include <hip/hip_runtime.h>

// ---------------------------------------------------------------------------
// GCN: 5x GCNConv + final linear.  N=100000, E=1.6M, D_IN=D_H=128, N_CLS=100.
//
// out_conv[v] = dinv[v] * ( sum_{e: dst=v} hs[src_e] + hs[v] ) + b,
//   where hs = (X @ W) * dinv[:,None],  dinv = rsqrt(deg+1).
// relu only after conv1.  final = h5 @ Wl + bl.
// ---------------------------------------------------------------------------

static __device__ __forceinline__ float f4get(const float4& v, int k) {
  switch (k) { case 0: return v.x; case 1: return v.y; case 2: return v.z; default: return v.w; }
}

// ---- edge dtype detection: if input is int64, odd int32 slots (hi words) are 0
__global__ void k_detect(const int* __restrict__ edge, int* __restrict__ flag) {
  int t = threadIdx.x;                       // 256 threads
  if (edge[2 * t + 1] != 0) atomicOr(flag, 1);  // flag=1 -> genuine int32 layout
}

static __device__ __forceinline__ int load_idx(const int* edge, const int* flag, size_t pos) {
  bool is64 = (*flag == 0);
  if (is64) return (int)((const long long*)edge)[pos];
  return edge[pos];
}

__global__ void k_count(const int* __restrict__ edge, const int* __restrict__ flag,
                        int* __restrict__ counts, int E) {
  int i = blockIdx.x * 256 + threadIdx.x;
  if (i >= E) return;
  int d = load_idx(edge, flag, (size_t)E + i);
  atomicAdd(&counts[d], 1);
}

__global__ void k_dinv(const int* __restrict__ counts, float* __restrict__ dinv, int n) {
  int i = blockIdx.x * 256 + threadIdx.x;
  if (i < n) dinv[i] = rsqrtf((float)counts[i] + 1.0f);
}

// ---- CSR build: chunk sums -> root scan -> per-chunk rescan ----
__global__ void k_chunksum(const int* __restrict__ counts, int* __restrict__ chunksums, int n) {
  __shared__ int sd[256];
  int t = threadIdx.x;
  int base = blockIdx.x * 1024 + t * 4;
  int s = 0;
#pragma unroll
  for (int j = 0; j < 4; ++j) { int i = base + j; if (i < n) s += counts[i]; }
  sd[t] = s; __syncthreads();
  for (int off = 128; off > 0; off >>= 1) {
    if (t < off) sd[t] += sd[t + off];
    __syncthreads();
  }
  if (t == 0) chunksums[blockIdx.x] = sd[0];
}

__global__ void k_root(const int* __restrict__ chunksums, int* __restrict__ chunkbase, int nchunks) {
  __shared__ int sc[128];
  int t = threadIdx.x;                       // 128 threads; nchunks <= 128
  int v = (t < nchunks) ? chunksums[t] : 0;
  sc[t] = v; __syncthreads();
  for (int off = 1; off < 128; off <<= 1) {
    int x = (t >= off) ? sc[t - off] : 0;
    __syncthreads();
    sc[t] += x;
    __syncthreads();
  }
  if (t < nchunks) chunkbase[t] = sc[t] - v;  // exclusive
}

__global__ void k_scan3(const int* __restrict__ counts, const int* __restrict__ chunkbase,
                        int* __restrict__ offsets, int* __restrict__ cursor, int n, int E) {
  __shared__ int sd[256];
  int t = threadIdx.x;
  int base = blockIdx.x * 1024 + t * 4;
  int c[4]; int s = 0;
#pragma unroll
  for (int j = 0; j < 4; ++j) { int i = base + j; c[j] = (i < n) ? counts[i] : 0; s += c[j]; }
  sd[t] = s; __syncthreads();
  int v = s;
  for (int off = 1; off < 256; off <<= 1) {
    int x = (t >= off) ? sd[t - off] : 0;
    __syncthreads();
    sd[t] += x;
    __syncthreads();
  }
  int run = chunkbase[blockIdx.x] + sd[t] - v;
#pragma unroll
  for (int j = 0; j < 4; ++j) {
    int i = base + j;
    if (i < n) { offsets[i] = run; cursor[i] = run; }
    run += c[j];
  }
  if (blockIdx.x == 0 && t == 0) offsets[n] = E;
}

__global__ void k_fill(const int* __restrict__ edge, const int* __restrict__ flag,
                       int* __restrict__ cursor, int* __restrict__ col, int E) {
  int i = blockIdx.x * 256 + threadIdx.x;
  if (i >= E) return;
  int s = load_idx(edge, flag, (size_t)i);
  int d = load_idx(edge, flag, (size_t)E + i);
  int pos = atomicAdd(&cursor[d], 1);
  col[pos] = s;
}

// ---- matmul: out[r][c] = sum_k X[r][k] W[k][c], then *dinv (MODE 0) or +bias (MODE 1)
// 128-row tile per block, 256 threads, each thread: 8 rows (stride 16) x 8 cols.
template <int K, int KP, int M, int MP, int MODE>
__launch_bounds__(256, 1)
__global__ void k_mm(const float* __restrict__ X, const float* __restrict__ W,
                     const float* __restrict__ dinv, const float* __restrict__ bias,
                     float* __restrict__ out, int nrows) {
  __shared__ float Xs[128 * KP];
  __shared__ float Ws[K * MP];
  int tid = threadIdx.x;
  int row0 = blockIdx.x * 128;

  // load W into LDS (pad cols M..MP-1 with zeros when padded)
  if (M == MP) {
    for (int idx = tid * 4; idx < K * M; idx += 1024)
      *(float4*)&Ws[idx] = *(const float4*)&W[idx];
  } else {
    for (int idx = tid * 4; idx < K * M; idx += 1024) {
      float4 v = *(const float4*)&W[idx];
      int r = idx / M, cc = idx % M;           // M%4==0 -> cc%4==0, cc+3<M
      *(float4*)&Ws[r * MP + cc] = v;
    }
    for (int r = tid; r < K; r += 256)
      *(float4*)&Ws[r * MP + M] = make_float4(0.f, 0.f, 0.f, 0.f);  // MP-M==4
  }
  // load X tile (rows row0..row0+127), zero-fill past nrows
  const size_t tilebase = (size_t)row0 * K;
  for (int idx = tid * 4; idx < 128 * K; idx += 1024) {
    int r = idx / K, cc = idx % K;             // K%4==0
    float4 v = make_float4(0.f, 0.f, 0.f, 0.f);
    if (row0 + r < nrows) v = *(const float4*)&X[tilebase + idx];
    *(float4*)&Xs[r * KP + cc] = v;
  }
  __syncthreads();

  int tc = tid & 15, tr = tid >> 4;
  int c0 = tc * 8;
  float acc[8][8];
#pragma unroll
  for (int i = 0; i < 8; ++i)
#pragma unroll
    for (int j = 0; j < 8; ++j) acc[i][j] = 0.f;

  if (c0 < M) {
    for (int k = 0; k < K; k += 4) {
      float4 xf[8];
#pragma unroll
      for (int i = 0; i < 8; ++i) xf[i] = *(const float4*)&Xs[(tr + 16 * i) * KP + k];
      float4 wa[4], wb[4];
#pragma unroll
      for (int kk = 0; kk < 4; ++kk) {
        wa[kk] = *(const float4*)&Ws[(k + kk) * MP + c0];
        wb[kk] = *(const float4*)&Ws[(k + kk) * MP + c0 + 4];
      }
#pragma unroll
      for (int i = 0; i < 8; ++i) {
#pragma unroll
        for (int kk = 0; kk < 4; ++kk) {
          float xv = f4get(xf[i], kk);
          acc[i][0] = fmaf(xv, wa[kk].x, acc[i][0]);
          acc[i][1] = fmaf(xv, wa[kk].y, acc[i][1]);
          acc[i][2] = fmaf(xv, wa[kk].z, acc[i][2]);
          acc[i][3] = fmaf(xv, wa[kk].w, acc[i][3]);
          acc[i][4] = fmaf(xv, wb[kk].x, acc[i][4]);
          acc[i][5] = fmaf(xv, wb[kk].y, acc[i][5]);
          acc[i][6] = fmaf(xv, wb[kk].z, acc[i][6]);
          acc[i][7] = fmaf(xv, wb[kk].w, acc[i][7]);
        }
      }
    }
    // epilogue
#pragma unroll
    for (int i = 0; i < 8; ++i) {
      int grow = row0 + tr + 16 * i;
      if (grow >= nrows) continue;
      float* o = &out[(size_t)grow * M + c0];
      if (MODE == 0) {
        float sc = dinv[grow];
#pragma unroll
        for (int j = 0; j < 8; ++j)
          if (c0 + j < M) o[j] = acc[i][j] * sc;
      } else {
#pragma unroll
        for (int j = 0; j < 8; ++j)
          if (c0 + j < M) o[j] = acc[i][j] + bias[c0 + j];
      }
    }
  }
}

// ---- aggregation: one wave per node, float2 per lane over F cols ----
template <int F, bool RELU>
__global__ void k_agg(const float* __restrict__ hs, const int* __restrict__ offsets,
                      const int* __restrict__ col, const float* __restrict__ dinv,
                      const float* __restrict__ bias, float* __restrict__ out, int n) {
  int wid = (blockIdx.x * 256 + threadIdx.x) >> 6;
  int lane = threadIdx.x & 63;
  int c = lane * 2;
  if (wid >= n || c >= F) return;
  float2 self = *(const float2*)&hs[(size_t)wid * F + c];
  float ax = self.x, ay = self.y;
  int s = offsets[wid], e = offsets[wid + 1];
  for (int i = s; i < e; ++i) {
    int u = col[i];
    float2 m = *(const float2*)&hs[(size_t)u * F + c];
    ax += m.x; ay += m.y;
  }
  float w = dinv[wid];
  float rx = fmaf(ax, w, bias[c]);
  float ry = fmaf(ay, w, bias[c + 1]);
  if (RELU) { rx = fmaxf(rx, 0.f); ry = fmaxf(ry, 0.f); }
  *(float2*)&out[(size_t)wid * F + c] = make_float2(rx, ry);
}

// ---------------------------------------------------------------------------
extern "C" void kernel_launch(void* const* d_in, const int* in_sizes, int n_in,
                              void* d_out, int out_size, void* d_ws, size_t ws_size,
                              hipStream_t stream) {
  const float* x    = (const float*)d_in[0];
  const int*   edge = (const int*)d_in[1];
  const float* W1 = (const float*)d_in[2];  const float* b1 = (const float*)d_in[3];
  const float* W2 = (const float*)d_in[4];  const float* b2 = (const float*)d_in[5];
  const float* W3 = (const float*)d_in[6];  const float* b3 = (const float*)d_in[7];
  const float* W4 = (const float*)d_in[8];  const float* b4 = (const float*)d_in[9];
  const float* W5 = (const float*)d_in[10]; const float* b5 = (const float*)d_in[11];
  const float* Wl = (const float*)d_in[12]; const float* bl = (const float*)d_in[13];

  const int N = in_sizes[0] / 128;
  const int E = in_sizes[1] / 2;

  // workspace carve (256B aligned)
  char* ws = (char*)d_ws;
  size_t cur = 0;
  auto alloc = [&](size_t bytes) -> char* {
    char* p = ws + cur;
    cur = (cur + bytes + 255) & ~(size_t)255;
    return p;
  };
  int*   counts    = (int*)alloc((size_t)N * 4);
  int*   flag      = (int*)alloc(4);
  int*   offsets   = (int*)alloc((size_t)(N + 1) * 4);
  int*   cursor    = (int*)alloc((size_t)N * 4);
  float* dinv      = (float*)alloc((size_t)N * 4);
  int*   chunksums = (int*)alloc(128 * 4);
  int*   chunkbase = (int*)alloc(128 * 4);
  int*   col       = (int*)alloc((size_t)E * 4);
  float* bufA      = (float*)alloc((size_t)N * 128 * 4);
  float* bufB      = (float*)alloc((size_t)N * 128 * 4);
  (void)ws_size; (void)n_in; (void)out_size;

  hipMemsetAsync(counts, 0, (size_t)N * 4, stream);
  hipMemsetAsync(flag, 0, 4, stream);

  const int nchunks = (N + 1023) / 1024;
  const int egrid = (E + 255) / 256;
  const int ngrid = (N + 255) / 256;

  k_detect<<<1, 256, 0, stream>>>(edge, flag);
  k_count<<<egrid, 256, 0, stream>>>(edge, flag, counts, E);
  k_dinv<<<ngrid, 256, 0, stream>>>(counts, dinv, N);
  k_chunksum<<<nchunks, 256, 0, stream>>>(counts, chunksums, N);
  k_root<<<1, 128, 0, stream>>>(chunksums, chunkbase, nchunks);
  k_scan3<<<nchunks, 256, 0, stream>>>(counts, chunkbase, offsets, cursor, N, E);
  k_fill<<<egrid, 256, 0, stream>>>(edge, flag, cursor, col, E);

  const int mmgrid = (N + 127) / 128;
  const int agrid = (N + 3) / 4;

  // layer 1 (relu)
  k_mm<128, 132, 128, 128, 0><<<mmgrid, 256, 0, stream>>>(x, W1, dinv, nullptr, bufA, N);
  k_agg<128, true><<<agrid, 256, 0, stream>>>(bufA, offsets, col, dinv, b1, bufB, N);
  // layer 2
  k_mm<128, 132, 128, 128, 0><<<mmgrid, 256, 0, stream>>>(bufB, W2, dinv, nullptr, bufA, N);
  k_agg<128, false><<<agrid, 256, 0, stream>>>(bufA, offsets, col, dinv, b2, bufB, N);
  // layer 3
  k_mm<128, 132, 128, 128, 0><<<mmgrid, 256, 0, stream>>>(bufB, W3, dinv, nullptr, bufA, N);
  k_agg<128, false><<<agrid, 256, 0, stream>>>(bufA, offsets, col, dinv, b3, bufB, N);
  // layer 4
  k_mm<128, 132, 128, 128, 0><<<mmgrid, 256, 0, stream>>>(bufB, W4, dinv, nullptr, bufA, N);
  k_agg<128, false><<<agrid, 256, 0, stream>>>(bufA, offsets, col, dinv, b4, bufB, N);
  // layer 5 (F_out = 100)
  k_mm<128, 132, 100, 104, 0><<<mmgrid, 256, 0, stream>>>(bufB, W5, dinv, nullptr, bufA, N);
  k_agg<100, false><<<agrid, 256, 0, stream>>>(bufA, offsets, col, dinv, b5, bufB, N);
  // final linear -> d_out
  k_mm<100, 116, 100, 104, 1><<<mmgrid, 256, 0, stream>>>(bufB, Wl, nullptr, bl, (float*)d_out, N);
}

// Round 2
// 1236.164 us; speedup vs baseline: 1.3002x; 1.3002x over previous
//
#include <hip/hip_runtime.h>

// ---------------------------------------------------------------------------
// GCN: 5x GCNConv + final linear.  N=100000, E=1.6M, D_IN=D_H=128, N_CLS=100.
//
// Algebra: S = D^{-1/2}(A+I)D^{-1/2}.  conv_i(h) = S h W_i + 1 b_i^T.
// relu only after conv1.  Collapsed:
//   h1  = relu(S x W1 + 1 b1^T)
//   out = S^4 h1 Wc + S^3 1 c2^T + S^2 1 c3^T + S 1 c4^T + 1 cb^T
// with Wc = W2W3W4W5Wl,  c2 = R3^T b2, c3 = R4^T b3, c4 = R5^T b4,
//      cb = Wl^T b5 + bl,  R5 = W5Wl, R4 = W4R5, R3 = W3R4.
// Weight-chain products computed on-device in fp64 (tiny).
// ---------------------------------------------------------------------------

static __device__ __forceinline__ float f4get(const float4& v, int k) {
  switch (k) { case 0: return v.x; case 1: return v.y; case 2: return v.z; default: return v.w; }
}

// ---- edge dtype detection: if input is int64, odd int32 slots (hi words) are 0
__global__ void k_detect(const int* __restrict__ edge, int* __restrict__ flag) {
  int t = threadIdx.x;                       // 256 threads
  if (edge[2 * t + 1] != 0) atomicOr(flag, 1);  // flag=1 -> genuine int32 layout
}

static __device__ __forceinline__ int load_idx(const int* edge, const int* flag, size_t pos) {
  bool is64 = (*flag == 0);
  if (is64) return (int)((const long long*)edge)[pos];
  return edge[pos];
}

__global__ void k_count(const int* __restrict__ edge, const int* __restrict__ flag,
                        int* __restrict__ counts, int E) {
  int i = blockIdx.x * 256 + threadIdx.x;
  if (i >= E) return;
  int d = load_idx(edge, flag, (size_t)E + i);
  atomicAdd(&counts[d], 1);
}

__global__ void k_dinv(const int* __restrict__ counts, float* __restrict__ dinv, int n) {
  int i = blockIdx.x * 256 + threadIdx.x;
  if (i < n) dinv[i] = rsqrtf((float)counts[i] + 1.0f);
}

// ---- CSR build: chunk sums -> root scan -> per-chunk rescan ----
__global__ void k_chunksum(const int* __restrict__ counts, int* __restrict__ chunksums, int n) {
  __shared__ int sd[256];
  int t = threadIdx.x;
  int base = blockIdx.x * 1024 + t * 4;
  int s = 0;
#pragma unroll
  for (int j = 0; j < 4; ++j) { int i = base + j; if (i < n) s += counts[i]; }
  sd[t] = s; __syncthreads();
  for (int off = 128; off > 0; off >>= 1) {
    if (t < off) sd[t] += sd[t + off];
    __syncthreads();
  }
  if (t == 0) chunksums[blockIdx.x] = sd[0];
}

__global__ void k_root(const int* __restrict__ chunksums, int* __restrict__ chunkbase, int nchunks) {
  __shared__ int sc[128];
  int t = threadIdx.x;                       // 128 threads; nchunks <= 128
  int v = (t < nchunks) ? chunksums[t] : 0;
  sc[t] = v; __syncthreads();
  for (int off = 1; off < 128; off <<= 1) {
    int x = (t >= off) ? sc[t - off] : 0;
    __syncthreads();
    sc[t] += x;
    __syncthreads();
  }
  if (t < nchunks) chunkbase[t] = sc[t] - v;  // exclusive
}

__global__ void k_scan3(const int* __restrict__ counts, const int* __restrict__ chunkbase,
                        int* __restrict__ offsets, int* __restrict__ cursor, int n, int E) {
  __shared__ int sd[256];
  int t = threadIdx.x;
  int base = blockIdx.x * 1024 + t * 4;
  int c[4]; int s = 0;
#pragma unroll
  for (int j = 0; j < 4; ++j) { int i = base + j; c[j] = (i < n) ? counts[i] : 0; s += c[j]; }
  sd[t] = s; __syncthreads();
  int v = s;
  for (int off = 1; off < 256; off <<= 1) {
    int x = (t >= off) ? sd[t - off] : 0;
    __syncthreads();
    sd[t] += x;
    __syncthreads();
  }
  int run = chunkbase[blockIdx.x] + sd[t] - v;
#pragma unroll
  for (int j = 0; j < 4; ++j) {
    int i = base + j;
    if (i < n) { offsets[i] = run; cursor[i] = run; }
    run += c[j];
  }
  if (blockIdx.x == 0 && t == 0) offsets[n] = E;
}

__global__ void k_fill(const int* __restrict__ edge, const int* __restrict__ flag,
                       int* __restrict__ cursor, int* __restrict__ col, int E) {
  int i = blockIdx.x * 256 + threadIdx.x;
  if (i >= E) return;
  int s = load_idx(edge, flag, (size_t)i);
  int d = load_idx(edge, flag, (size_t)E + i);
  int pos = atomicAdd(&cursor[d], 1);
  col[pos] = s;
}

// ---- tiny fp64 matmul for the weight chain: C[MxNc] = A[MxK] B[KxNc] ----
template <typename TB>
__global__ void k_smm(const float* __restrict__ A, const TB* __restrict__ B,
                      double* __restrict__ C, int M, int K, int Nc) {
  int idx = blockIdx.x * 256 + threadIdx.x;
  if (idx >= M * Nc) return;
  int i = idx / Nc, j = idx % Nc;
  double acc = 0.0;
  for (int k = 0; k < K; ++k) acc += (double)A[i * K + k] * (double)B[k * Nc + j];
  C[idx] = acc;
}

__global__ void k_d2f(const double* __restrict__ in, float* __restrict__ out, int n) {
  int i = blockIdx.x * 256 + threadIdx.x;
  if (i < n) out[i] = (float)in[i];
}

// ---- bias-correction vectors: corr = [c2(128 slots), c3, c4, cb] ----
__global__ void k_cvec(const float* __restrict__ b2, const float* __restrict__ b3,
                       const float* __restrict__ b4, const float* __restrict__ b5,
                       const float* __restrict__ bl, const float* __restrict__ Wl,
                       const double* __restrict__ R3, const double* __restrict__ R4,
                       const double* __restrict__ R5, double* __restrict__ corr) {
  int j = threadIdx.x;                        // 128 threads, j<100 active
  if (j >= 100) { return; }
  double a2 = 0.0, a3 = 0.0, a4 = 0.0, acb = 0.0;
  for (int k = 0; k < 128; ++k) {
    a2 += (double)b2[k] * R3[k * 100 + j];
    a3 += (double)b3[k] * R4[k * 100 + j];
    a4 += (double)b4[k] * R5[k * 100 + j];
  }
  for (int k = 0; k < 100; ++k) acb += (double)b5[k] * (double)Wl[k * 100 + j];
  corr[j] = a2; corr[128 + j] = a3; corr[256 + j] = a4; corr[384 + j] = acb + (double)bl[j];
}

// ---- matmul: out[r][c] = (sum_k X[r][k] W[k][c]) * dinv[r]
// 128-row tile per block, 256 threads, each thread: 8 rows (stride 16) x 8 cols.
template <int K, int KP, int M, int MP>
__launch_bounds__(256, 1)
__global__ void k_mm(const float* __restrict__ X, const float* __restrict__ W,
                     const float* __restrict__ dinv, float* __restrict__ out, int nrows) {
  __shared__ float Xs[128 * KP];
  __shared__ float Ws[K * MP];
  int tid = threadIdx.x;
  int row0 = blockIdx.x * 128;

  if (M == MP) {
    for (int idx = tid * 4; idx < K * M; idx += 1024)
      *(float4*)&Ws[idx] = *(const float4*)&W[idx];
  } else {
    for (int idx = tid * 4; idx < K * M; idx += 1024) {
      float4 v = *(const float4*)&W[idx];
      int r = idx / M, cc = idx % M;           // M%4==0 -> cc%4==0
      *(float4*)&Ws[r * MP + cc] = v;
    }
    for (int r = tid; r < K; r += 256)
      *(float4*)&Ws[r * MP + M] = make_float4(0.f, 0.f, 0.f, 0.f);  // MP-M==4
  }
  const size_t tilebase = (size_t)row0 * K;
  for (int idx = tid * 4; idx < 128 * K; idx += 1024) {
    int r = idx / K;
    float4 v = make_float4(0.f, 0.f, 0.f, 0.f);
    if (row0 + r < nrows) v = *(const float4*)&X[tilebase + idx];
    *(float4*)&Xs[r * KP + (idx % K)] = v;
  }
  __syncthreads();

  int tc = tid & 15, tr = tid >> 4;
  int c0 = tc * 8;
  float acc[8][8];
#pragma unroll
  for (int i = 0; i < 8; ++i)
#pragma unroll
    for (int j = 0; j < 8; ++j) acc[i][j] = 0.f;

  if (c0 < M) {
    for (int k = 0; k < K; k += 4) {
      float4 xf[8];
#pragma unroll
      for (int i = 0; i < 8; ++i) xf[i] = *(const float4*)&Xs[(tr + 16 * i) * KP + k];
      float4 wa[4], wb[4];
#pragma unroll
      for (int kk = 0; kk < 4; ++kk) {
        wa[kk] = *(const float4*)&Ws[(k + kk) * MP + c0];
        wb[kk] = *(const float4*)&Ws[(k + kk) * MP + c0 + 4];
      }
#pragma unroll
      for (int i = 0; i < 8; ++i) {
#pragma unroll
        for (int kk = 0; kk < 4; ++kk) {
          float xv = f4get(xf[i], kk);
          acc[i][0] = fmaf(xv, wa[kk].x, acc[i][0]);
          acc[i][1] = fmaf(xv, wa[kk].y, acc[i][1]);
          acc[i][2] = fmaf(xv, wa[kk].z, acc[i][2]);
          acc[i][3] = fmaf(xv, wa[kk].w, acc[i][3]);
          acc[i][4] = fmaf(xv, wb[kk].x, acc[i][4]);
          acc[i][5] = fmaf(xv, wb[kk].y, acc[i][5]);
          acc[i][6] = fmaf(xv, wb[kk].z, acc[i][6]);
          acc[i][7] = fmaf(xv, wb[kk].w, acc[i][7]);
        }
      }
    }
#pragma unroll
    for (int i = 0; i < 8; ++i) {
      int grow = row0 + tr + 16 * i;
      if (grow >= nrows) continue;
      float* o = &out[(size_t)grow * M + c0];
      float sc = dinv[grow];
#pragma unroll
      for (int j = 0; j < 8; ++j)
        if (c0 + j < M) o[j] = acc[i][j] * sc;
    }
  }
}

// ---- aggregation: one wave per node, float2/lane, edge loop in masked groups of 8
// input hs is pre-scaled by dinv.  MODE 0: relu(dinv*sum + bias)   [layer 1]
// MODE 1: dinv^2*sum  (pre-scaled for next gather)  MODE 2: dinv*sum + rank-1 corr
template <int F, int MODE>
__global__ void k_agg(const float* __restrict__ hs, const int* __restrict__ offsets,
                      const int* __restrict__ col, const float* __restrict__ dinv,
                      const float* __restrict__ bias,
                      const float* __restrict__ s1, const float* __restrict__ s2,
                      const float* __restrict__ s3, const double* __restrict__ corr,
                      float* __restrict__ out, int n) {
  int wid = (blockIdx.x * 256 + threadIdx.x) >> 6;
  int lane = threadIdx.x & 63;
  int c = lane * 2;
  if (wid >= n) return;
  if (F != 128 && c >= F) return;
  float2 self = *(const float2*)&hs[(size_t)wid * F + c];
  float ax = self.x, ay = self.y;
  int s = offsets[wid], e = offsets[wid + 1];
  for (int i = s; i < e; i += 8) {
    float2 m[8];
#pragma unroll
    for (int j = 0; j < 8; ++j) {
      m[j] = make_float2(0.f, 0.f);
      if (i + j < e) {
        int u = col[i + j];
        m[j] = *(const float2*)&hs[(size_t)u * F + c];
      }
    }
#pragma unroll
    for (int j = 0; j < 8; ++j) { ax += m[j].x; ay += m[j].y; }
  }
  float w = dinv[wid];
  float rx, ry;
  if (MODE == 0) {
    rx = fmaxf(fmaf(ax, w, bias[c]), 0.f);
    ry = fmaxf(fmaf(ay, w, bias[c + 1]), 0.f);
  } else if (MODE == 1) {
    float w2 = w * w;
    rx = ax * w2; ry = ay * w2;
  } else {
    float v1 = s1[wid], v2 = s2[wid], v3 = s3[wid];
    rx = ax * w + v3 * (float)corr[c]     + v2 * (float)corr[128 + c]
               + v1 * (float)corr[256 + c] + (float)corr[384 + c];
    ry = ay * w + v3 * (float)corr[c + 1] + v2 * (float)corr[128 + c + 1]
               + v1 * (float)corr[256 + c + 1] + (float)corr[384 + c + 1];
  }
  *(float2*)&out[(size_t)wid * F + c] = make_float2(rx, ry);
}

// ---- scalar aggregation for s_k = S^k 1 (thread per node) ----
template <bool ONE>
__global__ void k_sagg(const float* __restrict__ prev, const int* __restrict__ offsets,
                       const int* __restrict__ col, const float* __restrict__ dinv,
                       float* __restrict__ out, int n) {
  int v = blockIdx.x * 256 + threadIdx.x;
  if (v >= n) return;
  int s = offsets[v], e = offsets[v + 1];
  float acc = 0.f;
  for (int i = s; i < e; i += 8) {
    float m[8];
#pragma unroll
    for (int j = 0; j < 8; ++j) {
      m[j] = 0.f;
      if (i + j < e) {
        int u = col[i + j];
        float p = ONE ? 1.0f : prev[u];
        m[j] = dinv[u] * p;
      }
    }
#pragma unroll
    for (int j = 0; j < 8; ++j) acc += m[j];
  }
  float dv = dinv[v];
  float pv = ONE ? 1.0f : prev[v];
  out[v] = dv * (acc + dv * pv);
}

// ---------------------------------------------------------------------------
extern "C" void kernel_launch(void* const* d_in, const int* in_sizes, int n_in,
                              void* d_out, int out_size, void* d_ws, size_t ws_size,
                              hipStream_t stream) {
  const float* x    = (const float*)d_in[0];
  const int*   edge = (const int*)d_in[1];
  const float* W1 = (const float*)d_in[2];  const float* b1 = (const float*)d_in[3];
  const float* W2 = (const float*)d_in[4];  const float* b2 = (const float*)d_in[5];
  const float* W3 = (const float*)d_in[6];  const float* b3 = (const float*)d_in[7];
  const float* W4 = (const float*)d_in[8];  const float* b4 = (const float*)d_in[9];
  const float* W5 = (const float*)d_in[10]; const float* b5 = (const float*)d_in[11];
  const float* Wl = (const float*)d_in[12]; const float* bl = (const float*)d_in[13];

  const int N = in_sizes[0] / 128;
  const int E = in_sizes[1] / 2;

  char* ws = (char*)d_ws;
  size_t cur = 0;
  auto alloc = [&](size_t bytes) -> char* {
    char* p = ws + cur;
    cur = (cur + bytes + 255) & ~(size_t)255;
    return p;
  };
  int*    counts    = (int*)alloc((size_t)N * 4);
  int*    flag      = (int*)alloc(4);
  int*    offsets   = (int*)alloc((size_t)(N + 1) * 4);
  int*    cursor    = (int*)alloc((size_t)N * 4);
  float*  dinv      = (float*)alloc((size_t)N * 4);
  int*    chunksums = (int*)alloc(128 * 4);
  int*    chunkbase = (int*)alloc(128 * 4);
  float*  s1        = (float*)alloc((size_t)N * 4);
  float*  s2        = (float*)alloc((size_t)N * 4);
  float*  s3        = (float*)alloc((size_t)N * 4);
  double* R5        = (double*)alloc(128 * 100 * 8);
  double* R4        = (double*)alloc(128 * 100 * 8);
  double* R3        = (double*)alloc(128 * 100 * 8);
  double* Wcd       = (double*)alloc(128 * 100 * 8);
  float*  Wc        = (float*)alloc(128 * 100 * 4);
  double* corr      = (double*)alloc(512 * 8);
  int*    col       = (int*)alloc((size_t)E * 4);
  float*  bufA      = (float*)alloc((size_t)N * 128 * 4);
  float*  bufB      = (float*)alloc((size_t)N * 128 * 4);
  (void)ws_size; (void)n_in; (void)out_size;

  hipMemsetAsync(counts, 0, (size_t)N * 4, stream);
  hipMemsetAsync(flag, 0, 4, stream);

  const int nchunks = (N + 1023) / 1024;
  const int egrid = (E + 255) / 256;
  const int ngrid = (N + 255) / 256;

  k_detect<<<1, 256, 0, stream>>>(edge, flag);
  k_count<<<egrid, 256, 0, stream>>>(edge, flag, counts, E);
  k_dinv<<<ngrid, 256, 0, stream>>>(counts, dinv, N);
  k_chunksum<<<nchunks, 256, 0, stream>>>(counts, chunksums, N);
  k_root<<<1, 128, 0, stream>>>(chunksums, chunkbase, nchunks);
  k_scan3<<<nchunks, 256, 0, stream>>>(counts, chunkbase, offsets, cursor, N, E);
  k_fill<<<egrid, 256, 0, stream>>>(edge, flag, cursor, col, E);

  // weight chain (fp64): R5 = W5 Wl; R4 = W4 R5; R3 = W3 R4; Wc = W2 R3
  const int sgrid = (128 * 100 + 255) / 256;
  k_smm<float><<<sgrid, 256, 0, stream>>>(W5, Wl, R5, 128, 100, 100);
  k_smm<double><<<sgrid, 256, 0, stream>>>(W4, R5, R4, 128, 128, 100);
  k_smm<double><<<sgrid, 256, 0, stream>>>(W3, R4, R3, 128, 128, 100);
  k_smm<double><<<sgrid, 256, 0, stream>>>(W2, R3, Wcd, 128, 128, 100);
  k_d2f<<<sgrid, 256, 0, stream>>>(Wcd, Wc, 128 * 100);
  k_cvec<<<1, 128, 0, stream>>>(b2, b3, b4, b5, bl, Wl, R3, R4, R5, corr);

  // s_k = S^k 1
  k_sagg<true><<<ngrid, 256, 0, stream>>>(nullptr, offsets, col, dinv, s1, N);
  k_sagg<false><<<ngrid, 256, 0, stream>>>(s1, offsets, col, dinv, s2, N);
  k_sagg<false><<<ngrid, 256, 0, stream>>>(s2, offsets, col, dinv, s3, N);

  const int mmgrid = (N + 127) / 128;
  const int agrid = (N + 3) / 4;

  // hs0 = (x W1) * dinv
  k_mm<128, 132, 128, 128><<<mmgrid, 256, 0, stream>>>(x, W1, dinv, bufA, N);
  // h1 = relu(dinv*(gather+self) + b1)
  k_agg<128, 0><<<agrid, 256, 0, stream>>>(bufA, offsets, col, dinv, b1,
                                           nullptr, nullptr, nullptr, nullptr, bufB, N);
  // g_scaled = (h1 Wc) * dinv   [N x 100]
  k_mm<128, 132, 100, 104><<<mmgrid, 256, 0, stream>>>(bufB, Wc, dinv, bufA, N);
  // three chained S applications (output pre-scaled)
  k_agg<100, 1><<<agrid, 256, 0, stream>>>(bufA, offsets, col, dinv, nullptr,
                                           nullptr, nullptr, nullptr, nullptr, bufB, N);
  k_agg<100, 1><<<agrid, 256, 0, stream>>>(bufB, offsets, col, dinv, nullptr,
                                           nullptr, nullptr, nullptr, nullptr, bufA, N);
  k_agg<100, 1><<<agrid, 256, 0, stream>>>(bufA, offsets, col, dinv, nullptr,
                                           nullptr, nullptr, nullptr, nullptr, bufB, N);
  // final S application + rank-1 bias corrections -> d_out
  k_agg<100, 2><<<agrid, 256, 0, stream>>>(bufB, offsets, col, dinv, nullptr,
                                           s1, s2, s3, corr, (float*)d_out, N);
}

// Round 3
// 1062.438 us; speedup vs baseline: 1.5128x; 1.1635x over previous
//
#include <hip/hip_runtime.h>

// ---------------------------------------------------------------------------
// GCN: 5x GCNConv + final linear.  N=100000, E=1.6M, D_IN=D_H=128, N_CLS=100.
//
// Algebra: S = D^{-1/2}(A+I)D^{-1/2}.  conv_i(h) = S h W_i + 1 b_i^T.
// relu only after conv1.  Collapsed:
//   h1  = relu(S x W1 + 1 b1^T)
//   out = S^4 h1 Wc + S^3 1 c2^T + S^2 1 c3^T + S 1 c4^T + 1 cb^T
// with Wc = W2W3W4W5Wl,  c2 = R3^T b2, c3 = R4^T b3, c4 = R5^T b4,
//      cb = Wl^T b5 + bl,  R5 = W5Wl, R4 = W4R5, R3 = W3R4  (fp64 on device).
// The s_k = S^k 1 vectors ride along as feature columns 100..102 (stride 104).
// ---------------------------------------------------------------------------

static __device__ __forceinline__ float f4get(const float4& v, int k) {
  switch (k) { case 0: return v.x; case 1: return v.y; case 2: return v.z; default: return v.w; }
}

// ---- edge dtype detection: if input is int64, odd int32 slots (hi words) are 0
__global__ void k_detect(const int* __restrict__ edge, int* __restrict__ flag) {
  int t = threadIdx.x;                       // 256 threads
  if (edge[2 * t + 1] != 0) atomicOr(flag, 1);  // flag=1 -> genuine int32 layout
}

static __device__ __forceinline__ int load_idx(const int* edge, const int* flag, size_t pos) {
  bool is64 = (*flag == 0);
  if (is64) return (int)((const long long*)edge)[pos];
  return edge[pos];
}

// count degrees AND record each edge's rank within its dst (coalesced write)
__global__ void k_count(const int* __restrict__ edge, const int* __restrict__ flag,
                        int* __restrict__ counts, int* __restrict__ rank, int E) {
  int i = blockIdx.x * 256 + threadIdx.x;
  if (i >= E) return;
  int d = load_idx(edge, flag, (size_t)E + i);
  rank[i] = atomicAdd(&counts[d], 1);
}

__global__ void k_dinv(const int* __restrict__ counts, float* __restrict__ dinv, int n) {
  int i = blockIdx.x * 256 + threadIdx.x;
  if (i < n) dinv[i] = rsqrtf((float)counts[i] + 1.0f);
}

// ---- CSR build: chunk sums -> root scan -> per-chunk rescan ----
__global__ void k_chunksum(const int* __restrict__ counts, int* __restrict__ chunksums, int n) {
  __shared__ int sd[256];
  int t = threadIdx.x;
  int base = blockIdx.x * 1024 + t * 4;
  int s = 0;
#pragma unroll
  for (int j = 0; j < 4; ++j) { int i = base + j; if (i < n) s += counts[i]; }
  sd[t] = s; __syncthreads();
  for (int off = 128; off > 0; off >>= 1) {
    if (t < off) sd[t] += sd[t + off];
    __syncthreads();
  }
  if (t == 0) chunksums[blockIdx.x] = sd[0];
}

__global__ void k_root(const int* __restrict__ chunksums, int* __restrict__ chunkbase, int nchunks) {
  __shared__ int sc[128];
  int t = threadIdx.x;                       // 128 threads; nchunks <= 128
  int v = (t < nchunks) ? chunksums[t] : 0;
  sc[t] = v; __syncthreads();
  for (int off = 1; off < 128; off <<= 1) {
    int x = (t >= off) ? sc[t - off] : 0;
    __syncthreads();
    sc[t] += x;
    __syncthreads();
  }
  if (t < nchunks) chunkbase[t] = sc[t] - v;  // exclusive
}

__global__ void k_scan3(const int* __restrict__ counts, const int* __restrict__ chunkbase,
                        int* __restrict__ offsets, int n, int E) {
  __shared__ int sd[256];
  int t = threadIdx.x;
  int base = blockIdx.x * 1024 + t * 4;
  int c[4]; int s = 0;
#pragma unroll
  for (int j = 0; j < 4; ++j) { int i = base + j; c[j] = (i < n) ? counts[i] : 0; s += c[j]; }
  sd[t] = s; __syncthreads();
  int v = s;
  for (int off = 1; off < 256; off <<= 1) {
    int x = (t >= off) ? sd[t - off] : 0;
    __syncthreads();
    sd[t] += x;
    __syncthreads();
  }
  int run = chunkbase[blockIdx.x] + sd[t] - v;
#pragma unroll
  for (int j = 0; j < 4; ++j) {
    int i = base + j;
    if (i < n) offsets[i] = run;
    run += c[j];
  }
  if (blockIdx.x == 0 && t == 0) offsets[n] = E;
}

// atomic-free CSR fill: position = offsets[dst] + precomputed rank
__global__ void k_fill(const int* __restrict__ edge, const int* __restrict__ flag,
                       const int* __restrict__ offsets, const int* __restrict__ rank,
                       int* __restrict__ col, int E) {
  int i = blockIdx.x * 256 + threadIdx.x;
  if (i >= E) return;
  int s = load_idx(edge, flag, (size_t)i);
  int d = load_idx(edge, flag, (size_t)E + i);
  col[offsets[d] + rank[i]] = s;
}

// ---- tiny fp64 matmul for the weight chain: C[MxNc] = A[MxK] B[KxNc] ----
template <typename TB>
__global__ void k_smm(const float* __restrict__ A, const TB* __restrict__ B,
                      double* __restrict__ C, int M, int K, int Nc) {
  int idx = blockIdx.x * 256 + threadIdx.x;
  if (idx >= M * Nc) return;
  int i = idx / Nc, j = idx % Nc;
  double acc = 0.0;
  for (int k = 0; k < K; ++k) acc += (double)A[i * K + k] * (double)B[k * Nc + j];
  C[idx] = acc;
}

__global__ void k_d2f(const double* __restrict__ in, float* __restrict__ out, int n) {
  int i = blockIdx.x * 256 + threadIdx.x;
  if (i < n) out[i] = (float)in[i];
}

// ---- bias-correction vectors: corr = [c2(128 slots), c3, c4, cb] ----
__global__ void k_cvec(const float* __restrict__ b2, const float* __restrict__ b3,
                       const float* __restrict__ b4, const float* __restrict__ b5,
                       const float* __restrict__ bl, const float* __restrict__ Wl,
                       const double* __restrict__ R3, const double* __restrict__ R4,
                       const double* __restrict__ R5, double* __restrict__ corr) {
  int j = threadIdx.x;                        // 128 threads, j<100 active
  if (j >= 100) { return; }
  double a2 = 0.0, a3 = 0.0, a4 = 0.0, acb = 0.0;
  for (int k = 0; k < 128; ++k) {
    a2 += (double)b2[k] * R3[k * 100 + j];
    a3 += (double)b3[k] * R4[k * 100 + j];
    a4 += (double)b4[k] * R5[k * 100 + j];
  }
  for (int k = 0; k < 100; ++k) acb += (double)b5[k] * (double)Wl[k * 100 + j];
  corr[j] = a2; corr[128 + j] = a3; corr[256 + j] = a4; corr[384 + j] = acb + (double)bl[j];
}

// ---- matmul: out[r][c] = (sum_k X[r][k] W[k][c]) * dinv[r], out stride OS.
// AUG: also write col 100 = dinv[r] (seed for the s-chain), cols 101..OS-1 = 0.
// 128-row tile per block, 256 threads, each thread: 8 rows (stride 16) x 8 cols.
template <int K, int KP, int M, int MP, int OS, int AUG>
__launch_bounds__(256, 1)
__global__ void k_mm(const float* __restrict__ X, const float* __restrict__ W,
                     const float* __restrict__ dinv, float* __restrict__ out, int nrows) {
  __shared__ float Xs[128 * KP];
  __shared__ float Ws[K * MP];
  int tid = threadIdx.x;
  int row0 = blockIdx.x * 128;

  if (M == MP) {
    for (int idx = tid * 4; idx < K * M; idx += 1024)
      *(float4*)&Ws[idx] = *(const float4*)&W[idx];
  } else {
    for (int idx = tid * 4; idx < K * M; idx += 1024) {
      float4 v = *(const float4*)&W[idx];
      int r = idx / M, cc = idx % M;           // M%4==0 -> cc%4==0
      *(float4*)&Ws[r * MP + cc] = v;
    }
    for (int r = tid; r < K; r += 256)
      *(float4*)&Ws[r * MP + M] = make_float4(0.f, 0.f, 0.f, 0.f);  // MP-M==4
  }
  const size_t tilebase = (size_t)row0 * K;
  for (int idx = tid * 4; idx < 128 * K; idx += 1024) {
    int r = idx / K;
    float4 v = make_float4(0.f, 0.f, 0.f, 0.f);
    if (row0 + r < nrows) v = *(const float4*)&X[tilebase + idx];
    *(float4*)&Xs[r * KP + (idx % K)] = v;
  }
  __syncthreads();

  int tc = tid & 15, tr = tid >> 4;
  int c0 = tc * 8;
  float acc[8][8];
#pragma unroll
  for (int i = 0; i < 8; ++i)
#pragma unroll
    for (int j = 0; j < 8; ++j) acc[i][j] = 0.f;

  if (c0 < M) {
    for (int k = 0; k < K; k += 4) {
      float4 xf[8];
#pragma unroll
      for (int i = 0; i < 8; ++i) xf[i] = *(const float4*)&Xs[(tr + 16 * i) * KP + k];
      float4 wa[4], wb[4];
#pragma unroll
      for (int kk = 0; kk < 4; ++kk) {
        wa[kk] = *(const float4*)&Ws[(k + kk) * MP + c0];
        wb[kk] = *(const float4*)&Ws[(k + kk) * MP + c0 + 4];
      }
#pragma unroll
      for (int i = 0; i < 8; ++i) {
#pragma unroll
        for (int kk = 0; kk < 4; ++kk) {
          float xv = f4get(xf[i], kk);
          acc[i][0] = fmaf(xv, wa[kk].x, acc[i][0]);
          acc[i][1] = fmaf(xv, wa[kk].y, acc[i][1]);
          acc[i][2] = fmaf(xv, wa[kk].z, acc[i][2]);
          acc[i][3] = fmaf(xv, wa[kk].w, acc[i][3]);
          acc[i][4] = fmaf(xv, wb[kk].x, acc[i][4]);
          acc[i][5] = fmaf(xv, wb[kk].y, acc[i][5]);
          acc[i][6] = fmaf(xv, wb[kk].z, acc[i][6]);
          acc[i][7] = fmaf(xv, wb[kk].w, acc[i][7]);
        }
      }
    }
#pragma unroll
    for (int i = 0; i < 8; ++i) {
      int grow = row0 + tr + 16 * i;
      if (grow >= nrows) continue;
      float* o = &out[(size_t)grow * OS + c0];
      float sc = dinv[grow];
#pragma unroll
      for (int j = 0; j < 8; ++j) {
        int colj = c0 + j;
        if (colj < M) o[j] = acc[i][j] * sc;
        else if (AUG && colj == 100) o[j] = sc;      // seed: dinv * 1
        else if (AUG && colj < OS)  o[j] = 0.f;
      }
    }
  }
}

// ---- aggregation: one wave per node, float2/lane, edge loads in groups of 16.
// MODE 0: out = relu(dinv*(sum+self) + bias)            [layer 1, width 128]
// MODE 1: out = dinv^2*(sum+self)  (pre-scaled);  if c==fresh -> dinv (seed)
// MODE 2: out = dinv*(sum+self) + s3*c2 + s2*c3 + s1*c4 + cb   [final, 100 cols]
template <int STRIDE, int WIDTH, int MODE>
__global__ void k_agg(const float* __restrict__ hs, const int* __restrict__ offsets,
                      const int* __restrict__ col, const float* __restrict__ dinv,
                      const float* __restrict__ bias, const double* __restrict__ corr,
                      float* __restrict__ out, int n, int fresh) {
  int wid = (blockIdx.x * 256 + threadIdx.x) >> 6;
  int lane = threadIdx.x & 63;
  int c = lane * 2;
  if (wid >= n) return;
  if (WIDTH != 128 && c >= WIDTH) return;
  const float* row = &hs[(size_t)wid * STRIDE];
  float2 self = *(const float2*)&row[c];
  float ax = self.x, ay = self.y;
  int s = offsets[wid], e = offsets[wid + 1];
  for (int i = s; i < e; i += 16) {
    float2 m[16];
#pragma unroll
    for (int j = 0; j < 16; ++j) {
      m[j] = make_float2(0.f, 0.f);
      if (i + j < e) {
        int u = col[i + j];
        m[j] = *(const float2*)&hs[(size_t)u * STRIDE + c];
      }
    }
#pragma unroll
    for (int j = 0; j < 16; ++j) { ax += m[j].x; ay += m[j].y; }
  }
  float w = dinv[wid];
  float rx, ry;
  if (MODE == 0) {
    rx = fmaxf(fmaf(ax, w, bias[c]), 0.f);
    ry = fmaxf(fmaf(ay, w, bias[c + 1]), 0.f);
    *(float2*)&out[(size_t)wid * STRIDE + c] = make_float2(rx, ry);
  } else if (MODE == 1) {
    float w2 = w * w;
    rx = ax * w2; ry = ay * w2;
    if (c == fresh) rx = w;             // seed column: dinv * 1
    else if (c + 1 == fresh) ry = w;
    *(float2*)&out[(size_t)wid * STRIDE + c] = make_float2(rx, ry);
  } else {
    float4 sv = *(const float4*)&row[100];   // {dinv*s3, dinv*s2, dinv*s1, 0}
    float inv_w = 1.0f / w;
    float v3 = sv.x * inv_w, v2 = sv.y * inv_w, v1 = sv.z * inv_w;
    rx = ax * w + v3 * (float)corr[c]     + v2 * (float)corr[128 + c]
               + v1 * (float)corr[256 + c] + (float)corr[384 + c];
    ry = ay * w + v3 * (float)corr[c + 1] + v2 * (float)corr[128 + c + 1]
               + v1 * (float)corr[256 + c + 1] + (float)corr[384 + c + 1];
    *(float2*)&out[(size_t)wid * 100 + c] = make_float2(rx, ry);
  }
}

// ---------------------------------------------------------------------------
extern "C" void kernel_launch(void* const* d_in, const int* in_sizes, int n_in,
                              void* d_out, int out_size, void* d_ws, size_t ws_size,
                              hipStream_t stream) {
  const float* x    = (const float*)d_in[0];
  const int*   edge = (const int*)d_in[1];
  const float* W1 = (const float*)d_in[2];  const float* b1 = (const float*)d_in[3];
  const float* W2 = (const float*)d_in[4];  const float* b2 = (const float*)d_in[5];
  const float* W3 = (const float*)d_in[6];  const float* b3 = (const float*)d_in[7];
  const float* W4 = (const float*)d_in[8];  const float* b4 = (const float*)d_in[9];
  const float* W5 = (const float*)d_in[10]; const float* b5 = (const float*)d_in[11];
  const float* Wl = (const float*)d_in[12]; const float* bl = (const float*)d_in[13];

  const int N = in_sizes[0] / 128;
  const int E = in_sizes[1] / 2;

  char* ws = (char*)d_ws;
  size_t cur = 0;
  auto alloc = [&](size_t bytes) -> char* {
    char* p = ws + cur;
    cur = (cur + bytes + 255) & ~(size_t)255;
    return p;
  };
  int*    counts    = (int*)alloc((size_t)N * 4);
  int*    flag      = (int*)alloc(4);
  int*    offsets   = (int*)alloc((size_t)(N + 1) * 4);
  float*  dinv      = (float*)alloc((size_t)N * 4);
  int*    chunksums = (int*)alloc(128 * 4);
  int*    chunkbase = (int*)alloc(128 * 4);
  double* R5        = (double*)alloc(128 * 100 * 8);
  double* R4        = (double*)alloc(128 * 100 * 8);
  double* R3        = (double*)alloc(128 * 100 * 8);
  double* Wcd       = (double*)alloc(128 * 100 * 8);
  float*  Wc        = (float*)alloc(128 * 100 * 4);
  double* corr      = (double*)alloc(512 * 8);
  int*    rank      = (int*)alloc((size_t)E * 4);
  int*    col       = (int*)alloc((size_t)E * 4);
  float*  bufA      = (float*)alloc((size_t)N * 128 * 4);
  float*  bufB      = (float*)alloc((size_t)N * 128 * 4);
  (void)ws_size; (void)n_in; (void)out_size;

  hipMemsetAsync(counts, 0, (size_t)N * 4, stream);
  hipMemsetAsync(flag, 0, 4, stream);

  const int nchunks = (N + 1023) / 1024;
  const int egrid = (E + 255) / 256;
  const int ngrid = (N + 255) / 256;

  k_detect<<<1, 256, 0, stream>>>(edge, flag);
  k_count<<<egrid, 256, 0, stream>>>(edge, flag, counts, rank, E);
  k_dinv<<<ngrid, 256, 0, stream>>>(counts, dinv, N);
  k_chunksum<<<nchunks, 256, 0, stream>>>(counts, chunksums, N);
  k_root<<<1, 128, 0, stream>>>(chunksums, chunkbase, nchunks);
  k_scan3<<<nchunks, 256, 0, stream>>>(counts, chunkbase, offsets, N, E);
  k_fill<<<egrid, 256, 0, stream>>>(edge, flag, offsets, rank, col, E);

  // weight chain (fp64): R5 = W5 Wl; R4 = W4 R5; R3 = W3 R4; Wc = W2 R3
  const int sgrid = (128 * 100 + 255) / 256;
  k_smm<float><<<sgrid, 256, 0, stream>>>(W5, Wl, R5, 128, 100, 100);
  k_smm<double><<<sgrid, 256, 0, stream>>>(W4, R5, R4, 128, 128, 100);
  k_smm<double><<<sgrid, 256, 0, stream>>>(W3, R4, R3, 128, 128, 100);
  k_smm<double><<<sgrid, 256, 0, stream>>>(W2, R3, Wcd, 128, 128, 100);
  k_d2f<<<sgrid, 256, 0, stream>>>(Wcd, Wc, 128 * 100);
  k_cvec<<<1, 128, 0, stream>>>(b2, b3, b4, b5, bl, Wl, R3, R4, R5, corr);

  const int mmgrid = (N + 127) / 128;
  const int agrid = (N + 3) / 4;

  // hs0 = (x W1) * dinv  [128 wide]
  k_mm<128, 132, 128, 128, 128, 0><<<mmgrid, 256, 0, stream>>>(x, W1, dinv, bufA, N);
  // h1 = relu(dinv*(gather+self) + b1)  [128 wide]
  k_agg<128, 128, 0><<<agrid, 256, 0, stream>>>(bufA, offsets, col, dinv, b1, nullptr, bufB, N, 0);
  // g_scaled = (h1 Wc) * dinv, augmented: col100 = dinv  [stride 104]
  k_mm<128, 132, 100, 104, 104, 1><<<mmgrid, 256, 0, stream>>>(bufB, Wc, dinv, bufA, N);
  // three chained S applications (pre-scaled); s-chain rides in cols 100..102
  k_agg<104, 104, 1><<<agrid, 256, 0, stream>>>(bufA, offsets, col, dinv, nullptr, nullptr, bufB, N, 101);
  k_agg<104, 104, 1><<<agrid, 256, 0, stream>>>(bufB, offsets, col, dinv, nullptr, nullptr, bufA, N, 102);
  k_agg<104, 104, 1><<<agrid, 256, 0, stream>>>(bufA, offsets, col, dinv, nullptr, nullptr, bufB, N, -1);
  // final S application + rank-1 bias corrections -> d_out [100 wide]
  k_agg<104, 100, 2><<<agrid, 256, 0, stream>>>(bufB, offsets, col, dinv, nullptr, corr, (float*)d_out, N, -1);
}

// Round 4
// 952.330 us; speedup vs baseline: 1.6877x; 1.1156x over previous
//
#include <hip/hip_runtime.h>

// ---------------------------------------------------------------------------
// GCN: 5x GCNConv + final linear.  N=100000, E=1.6M, D_IN=D_H=128, N_CLS=100.
//
// Algebra: S = D^{-1/2}(A+I)D^{-1/2}.  conv_i(h) = S h W_i + 1 b_i^T.
// relu only after conv1.  Collapsed:
//   h1  = relu(S x W1 + 1 b1^T)
//   out = S^4 h1 Wc + S^3 1 c2^T + S^2 1 c3^T + S 1 c4^T + 1 cb^T
// with Wc = W2W3W4W5Wl,  c2 = R3^T b2, c3 = R4^T b3, c4 = R5^T b4,
//      cb = Wl^T b5 + bl  (weight chain in fp64 on device).
// s_k = S^k 1 ride along as feature columns 100..102 (stride 104).
// All gathered feature blocks stored fp16 (halves gather traffic; accum fp32).
// ---------------------------------------------------------------------------

typedef _Float16 h16;
typedef _Float16 __attribute__((ext_vector_type(2))) h16x2;
typedef _Float16 __attribute__((ext_vector_type(8))) h16x8;

static __device__ __forceinline__ float f4get(const float4& v, int k) {
  switch (k) { case 0: return v.x; case 1: return v.y; case 2: return v.z; default: return v.w; }
}

// ---- edge dtype detection: if input is int64, odd int32 slots (hi words) are 0
__global__ void k_detect(const int* __restrict__ edge, int* __restrict__ flag) {
  int t = threadIdx.x;                       // 256 threads
  if (edge[2 * t + 1] != 0) atomicOr(flag, 1);  // flag=1 -> genuine int32 layout
}

static __device__ __forceinline__ int load_idx(const int* edge, const int* flag, size_t pos) {
  bool is64 = (*flag == 0);
  if (is64) return (int)((const long long*)edge)[pos];
  return edge[pos];
}

// count degrees AND record each edge's rank within its dst (coalesced write)
__global__ void k_count(const int* __restrict__ edge, const int* __restrict__ flag,
                        int* __restrict__ counts, int* __restrict__ rank, int E) {
  int i = blockIdx.x * 256 + threadIdx.x;
  if (i >= E) return;
  int d = load_idx(edge, flag, (size_t)E + i);
  rank[i] = atomicAdd(&counts[d], 1);
}

__global__ void k_dinv(const int* __restrict__ counts, float* __restrict__ dinv, int n) {
  int i = blockIdx.x * 256 + threadIdx.x;
  if (i < n) dinv[i] = rsqrtf((float)counts[i] + 1.0f);
}

// ---- CSR build: chunk sums -> root scan -> per-chunk rescan ----
__global__ void k_chunksum(const int* __restrict__ counts, int* __restrict__ chunksums, int n) {
  __shared__ int sd[256];
  int t = threadIdx.x;
  int base = blockIdx.x * 1024 + t * 4;
  int s = 0;
#pragma unroll
  for (int j = 0; j < 4; ++j) { int i = base + j; if (i < n) s += counts[i]; }
  sd[t] = s; __syncthreads();
  for (int off = 128; off > 0; off >>= 1) {
    if (t < off) sd[t] += sd[t + off];
    __syncthreads();
  }
  if (t == 0) chunksums[blockIdx.x] = sd[0];
}

__global__ void k_root(const int* __restrict__ chunksums, int* __restrict__ chunkbase, int nchunks) {
  __shared__ int sc[128];
  int t = threadIdx.x;                       // 128 threads; nchunks <= 128
  int v = (t < nchunks) ? chunksums[t] : 0;
  sc[t] = v; __syncthreads();
  for (int off = 1; off < 128; off <<= 1) {
    int x = (t >= off) ? sc[t - off] : 0;
    __syncthreads();
    sc[t] += x;
    __syncthreads();
  }
  if (t < nchunks) chunkbase[t] = sc[t] - v;  // exclusive
}

__global__ void k_scan3(const int* __restrict__ counts, const int* __restrict__ chunkbase,
                        int* __restrict__ offsets, int n, int E) {
  __shared__ int sd[256];
  int t = threadIdx.x;
  int base = blockIdx.x * 1024 + t * 4;
  int c[4]; int s = 0;
#pragma unroll
  for (int j = 0; j < 4; ++j) { int i = base + j; c[j] = (i < n) ? counts[i] : 0; s += c[j]; }
  sd[t] = s; __syncthreads();
  int v = s;
  for (int off = 1; off < 256; off <<= 1) {
    int x = (t >= off) ? sd[t - off] : 0;
    __syncthreads();
    sd[t] += x;
    __syncthreads();
  }
  int run = chunkbase[blockIdx.x] + sd[t] - v;
#pragma unroll
  for (int j = 0; j < 4; ++j) {
    int i = base + j;
    if (i < n) offsets[i] = run;
    run += c[j];
  }
  if (blockIdx.x == 0 && t == 0) offsets[n] = E;
}

// atomic-free CSR fill: position = offsets[dst] + precomputed rank
__global__ void k_fill(const int* __restrict__ edge, const int* __restrict__ flag,
                       const int* __restrict__ offsets, const int* __restrict__ rank,
                       int* __restrict__ col, int E) {
  int i = blockIdx.x * 256 + threadIdx.x;
  if (i >= E) return;
  int s = load_idx(edge, flag, (size_t)i);
  int d = load_idx(edge, flag, (size_t)E + i);
  col[offsets[d] + rank[i]] = s;
}

// ---- tiny fp64 matmul for the weight chain: C[MxNc] = A[MxK] B[KxNc] ----
template <typename TB>
__global__ void k_smm(const float* __restrict__ A, const TB* __restrict__ B,
                      double* __restrict__ C, int M, int K, int Nc) {
  int idx = blockIdx.x * 256 + threadIdx.x;
  if (idx >= M * Nc) return;
  int i = idx / Nc, j = idx % Nc;
  double acc = 0.0;
  for (int k = 0; k < K; ++k) acc += (double)A[i * K + k] * (double)B[k * Nc + j];
  C[idx] = acc;
}

__global__ void k_d2f(const double* __restrict__ in, float* __restrict__ out, int n) {
  int i = blockIdx.x * 256 + threadIdx.x;
  if (i < n) out[i] = (float)in[i];
}

// ---- bias-correction vectors: corr = [c2(128 slots), c3, c4, cb] ----
__global__ void k_cvec(const float* __restrict__ b2, const float* __restrict__ b3,
                       const float* __restrict__ b4, const float* __restrict__ b5,
                       const float* __restrict__ bl, const float* __restrict__ Wl,
                       const double* __restrict__ R3, const double* __restrict__ R4,
                       const double* __restrict__ R5, double* __restrict__ corr) {
  int j = threadIdx.x;                        // 128 threads, j<100 active
  if (j >= 100) { return; }
  double a2 = 0.0, a3 = 0.0, a4 = 0.0, acb = 0.0;
  for (int k = 0; k < 128; ++k) {
    a2 += (double)b2[k] * R3[k * 100 + j];
    a3 += (double)b3[k] * R4[k * 100 + j];
    a4 += (double)b4[k] * R5[k * 100 + j];
  }
  for (int k = 0; k < 100; ++k) acb += (double)b5[k] * (double)Wl[k * 100 + j];
  corr[j] = a2; corr[128 + j] = a3; corr[256 + j] = a4; corr[384 + j] = acb + (double)bl[j];
}

// ---- matmul: out[r][c] = (sum_k X[r][k] W[k][c]) * dinv[r], fp16 out, stride OS.
// AUG: also write col 100 = dinv[r] (seed for the s-chain), cols 101..OS-1 = 0.
// X may be fp32 or fp16.  128-row tile, 256 threads, 8x8 register tile each.
template <typename TX, int K, int KP, int M, int MP, int OS, int AUG>
__launch_bounds__(256, 1)
__global__ void k_mm(const TX* __restrict__ X, const float* __restrict__ W,
                     const float* __restrict__ dinv, h16* __restrict__ out, int nrows) {
  __shared__ float Xs[128 * KP];
  __shared__ float Ws[K * MP];
  int tid = threadIdx.x;
  int row0 = blockIdx.x * 128;

  if (M == MP) {
    for (int idx = tid * 4; idx < K * M; idx += 1024)
      *(float4*)&Ws[idx] = *(const float4*)&W[idx];
  } else {
    for (int idx = tid * 4; idx < K * M; idx += 1024) {
      float4 v = *(const float4*)&W[idx];
      int r = idx / M, cc = idx % M;           // M%4==0 -> cc%4==0
      *(float4*)&Ws[r * MP + cc] = v;
    }
    for (int r = tid; r < K; r += 256)
      *(float4*)&Ws[r * MP + M] = make_float4(0.f, 0.f, 0.f, 0.f);  // MP-M==4
  }
  const size_t tilebase = (size_t)row0 * K;
  if (sizeof(TX) == 4) {
    for (int idx = tid * 4; idx < 128 * K; idx += 1024) {
      int r = idx / K;
      float4 v = make_float4(0.f, 0.f, 0.f, 0.f);
      if (row0 + r < nrows) v = *(const float4*)&((const float*)X)[tilebase + idx];
      *(float4*)&Xs[r * KP + (idx % K)] = v;
    }
  } else {
    for (int idx = tid * 8; idx < 128 * K; idx += 2048) {   // K%8==0
      int r = idx / K, cc = idx % K;
      float f[8];
#pragma unroll
      for (int q = 0; q < 8; ++q) f[q] = 0.f;
      if (row0 + r < nrows) {
        h16x8 v8 = *(const h16x8*)&((const h16*)X)[tilebase + idx];
#pragma unroll
        for (int q = 0; q < 8; ++q) f[q] = (float)v8[q];
      }
      *(float4*)&Xs[r * KP + cc]     = make_float4(f[0], f[1], f[2], f[3]);
      *(float4*)&Xs[r * KP + cc + 4] = make_float4(f[4], f[5], f[6], f[7]);
    }
  }
  __syncthreads();

  int tc = tid & 15, tr = tid >> 4;
  int c0 = tc * 8;
  float acc[8][8];
#pragma unroll
  for (int i = 0; i < 8; ++i)
#pragma unroll
    for (int j = 0; j < 8; ++j) acc[i][j] = 0.f;

  if (c0 < M) {
    for (int k = 0; k < K; k += 4) {
      float4 xf[8];
#pragma unroll
      for (int i = 0; i < 8; ++i) xf[i] = *(const float4*)&Xs[(tr + 16 * i) * KP + k];
      float4 wa[4], wb[4];
#pragma unroll
      for (int kk = 0; kk < 4; ++kk) {
        wa[kk] = *(const float4*)&Ws[(k + kk) * MP + c0];
        wb[kk] = *(const float4*)&Ws[(k + kk) * MP + c0 + 4];
      }
#pragma unroll
      for (int i = 0; i < 8; ++i) {
#pragma unroll
        for (int kk = 0; kk < 4; ++kk) {
          float xv = f4get(xf[i], kk);
          acc[i][0] = fmaf(xv, wa[kk].x, acc[i][0]);
          acc[i][1] = fmaf(xv, wa[kk].y, acc[i][1]);
          acc[i][2] = fmaf(xv, wa[kk].z, acc[i][2]);
          acc[i][3] = fmaf(xv, wa[kk].w, acc[i][3]);
          acc[i][4] = fmaf(xv, wb[kk].x, acc[i][4]);
          acc[i][5] = fmaf(xv, wb[kk].y, acc[i][5]);
          acc[i][6] = fmaf(xv, wb[kk].z, acc[i][6]);
          acc[i][7] = fmaf(xv, wb[kk].w, acc[i][7]);
        }
      }
    }
#pragma unroll
    for (int i = 0; i < 8; ++i) {
      int grow = row0 + tr + 16 * i;
      if (grow >= nrows) continue;
      h16* o = &out[(size_t)grow * OS + c0];
      float sc = dinv[grow];
#pragma unroll
      for (int j = 0; j < 8; j += 2) {
        int colj = c0 + j;
        if (colj >= OS) continue;
        float v0 = (colj < M) ? acc[i][j] * sc
                 : (AUG && colj == 100 ? sc : 0.f);
        float v1 = (colj + 1 < M) ? acc[i][j + 1] * sc
                 : (AUG && colj + 1 == 100 ? sc : 0.f);
        h16x2 p; p.x = (h16)v0; p.y = (h16)v1;
        *(h16x2*)&o[j] = p;
      }
    }
  }
}

// ---- aggregation: one wave per node, h16x2/lane, edge loads in groups of 16.
// MODE 0: out = relu(dinv*(sum+self) + bias)            [layer 1, width 128]
// MODE 1: out = dinv^2*(sum+self)  (pre-scaled);  if c==fresh -> dinv (seed)
// MODE 2: out = dinv*(sum+self) + s3*c2 + s2*c3 + s1*c4 + cb   [final, fp32 out]
template <int STRIDE, int WIDTH, int MODE, typename TOUT>
__global__ void k_agg(const h16* __restrict__ hs, const int* __restrict__ offsets,
                      const int* __restrict__ col, const float* __restrict__ dinv,
                      const float* __restrict__ bias, const double* __restrict__ corr,
                      TOUT* __restrict__ out, int n, int fresh) {
  int wid = (blockIdx.x * 256 + threadIdx.x) >> 6;
  int lane = threadIdx.x & 63;
  int c = lane * 2;
  if (wid >= n) return;
  if (WIDTH != 128 && c >= WIDTH) return;
  const h16* row = &hs[(size_t)wid * STRIDE];
  h16x2 self = *(const h16x2*)&row[c];
  float ax = (float)self.x, ay = (float)self.y;
  int s = offsets[wid], e = offsets[wid + 1];
  for (int i = s; i < e; i += 16) {
    h16x2 m[16];
#pragma unroll
    for (int j = 0; j < 16; ++j) {
      m[j].x = (h16)0.f; m[j].y = (h16)0.f;
      if (i + j < e) {
        int u = col[i + j];
        m[j] = *(const h16x2*)&hs[(size_t)u * STRIDE + c];
      }
    }
#pragma unroll
    for (int j = 0; j < 16; ++j) { ax += (float)m[j].x; ay += (float)m[j].y; }
  }
  float w = dinv[wid];
  float rx, ry;
  if (MODE == 0) {
    rx = fmaxf(fmaf(ax, w, bias[c]), 0.f);
    ry = fmaxf(fmaf(ay, w, bias[c + 1]), 0.f);
    h16x2 p; p.x = (h16)rx; p.y = (h16)ry;
    *(h16x2*)&((h16*)out)[(size_t)wid * STRIDE + c] = p;
  } else if (MODE == 1) {
    float w2 = w * w;
    rx = ax * w2; ry = ay * w2;
    if (c == fresh) rx = w;             // seed column: dinv * 1
    else if (c + 1 == fresh) ry = w;
    h16x2 p; p.x = (h16)rx; p.y = (h16)ry;
    *(h16x2*)&((h16*)out)[(size_t)wid * STRIDE + c] = p;
  } else {
    float inv_w = 1.0f / w;
    float v3 = (float)row[100] * inv_w;
    float v2 = (float)row[101] * inv_w;
    float v1 = (float)row[102] * inv_w;
    rx = ax * w + v3 * (float)corr[c]     + v2 * (float)corr[128 + c]
               + v1 * (float)corr[256 + c] + (float)corr[384 + c];
    ry = ay * w + v3 * (float)corr[c + 1] + v2 * (float)corr[128 + c + 1]
               + v1 * (float)corr[256 + c + 1] + (float)corr[384 + c + 1];
    *(float2*)&((float*)out)[(size_t)wid * 100 + c] = make_float2(rx, ry);
  }
}

// ---------------------------------------------------------------------------
extern "C" void kernel_launch(void* const* d_in, const int* in_sizes, int n_in,
                              void* d_out, int out_size, void* d_ws, size_t ws_size,
                              hipStream_t stream) {
  const float* x    = (const float*)d_in[0];
  const int*   edge = (const int*)d_in[1];
  const float* W1 = (const float*)d_in[2];  const float* b1 = (const float*)d_in[3];
  const float* W2 = (const float*)d_in[4];  const float* b2 = (const float*)d_in[5];
  const float* W3 = (const float*)d_in[6];  const float* b3 = (const float*)d_in[7];
  const float* W4 = (const float*)d_in[8];  const float* b4 = (const float*)d_in[9];
  const float* W5 = (const float*)d_in[10]; const float* b5 = (const float*)d_in[11];
  const float* Wl = (const float*)d_in[12]; const float* bl = (const float*)d_in[13];

  const int N = in_sizes[0] / 128;
  const int E = in_sizes[1] / 2;

  char* ws = (char*)d_ws;
  size_t cur = 0;
  auto alloc = [&](size_t bytes) -> char* {
    char* p = ws + cur;
    cur = (cur + bytes + 255) & ~(size_t)255;
    return p;
  };
  int*    counts    = (int*)alloc((size_t)N * 4);
  int*    flag      = (int*)alloc(4);
  int*    offsets   = (int*)alloc((size_t)(N + 1) * 4);
  float*  dinv      = (float*)alloc((size_t)N * 4);
  int*    chunksums = (int*)alloc(128 * 4);
  int*    chunkbase = (int*)alloc(128 * 4);
  double* R5        = (double*)alloc(128 * 100 * 8);
  double* R4        = (double*)alloc(128 * 100 * 8);
  double* R3        = (double*)alloc(128 * 100 * 8);
  double* Wcd       = (double*)alloc(128 * 100 * 8);
  float*  Wc        = (float*)alloc(128 * 100 * 4);
  double* corr      = (double*)alloc(512 * 8);
  int*    rank      = (int*)alloc((size_t)E * 4);
  int*    col       = (int*)alloc((size_t)E * 4);
  h16*    bufA      = (h16*)alloc((size_t)N * 128 * 2);
  h16*    bufB      = (h16*)alloc((size_t)N * 128 * 2);
  (void)ws_size; (void)n_in; (void)out_size;

  hipMemsetAsync(counts, 0, (size_t)N * 4, stream);
  hipMemsetAsync(flag, 0, 4, stream);

  const int nchunks = (N + 1023) / 1024;
  const int egrid = (E + 255) / 256;
  const int ngrid = (N + 255) / 256;

  k_detect<<<1, 256, 0, stream>>>(edge, flag);
  k_count<<<egrid, 256, 0, stream>>>(edge, flag, counts, rank, E);
  k_dinv<<<ngrid, 256, 0, stream>>>(counts, dinv, N);
  k_chunksum<<<nchunks, 256, 0, stream>>>(counts, chunksums, N);
  k_root<<<1, 128, 0, stream>>>(chunksums, chunkbase, nchunks);
  k_scan3<<<nchunks, 256, 0, stream>>>(counts, chunkbase, offsets, N, E);
  k_fill<<<egrid, 256, 0, stream>>>(edge, flag, offsets, rank, col, E);

  // weight chain (fp64): R5 = W5 Wl; R4 = W4 R5; R3 = W3 R4; Wc = W2 R3
  const int sgrid = (128 * 100 + 255) / 256;
  k_smm<float><<<sgrid, 256, 0, stream>>>(W5, Wl, R5, 128, 100, 100);
  k_smm<double><<<sgrid, 256, 0, stream>>>(W4, R5, R4, 128, 128, 100);
  k_smm<double><<<sgrid, 256, 0, stream>>>(W3, R4, R3, 128, 128, 100);
  k_smm<double><<<sgrid, 256, 0, stream>>>(W2, R3, Wcd, 128, 128, 100);
  k_d2f<<<sgrid, 256, 0, stream>>>(Wcd, Wc, 128 * 100);
  k_cvec<<<1, 128, 0, stream>>>(b2, b3, b4, b5, bl, Wl, R3, R4, R5, corr);

  const int mmgrid = (N + 127) / 128;
  const int agrid = (N + 3) / 4;

  // hs0 = (x W1) * dinv  [fp16, stride 128]
  k_mm<float, 128, 132, 128, 128, 128, 0><<<mmgrid, 256, 0, stream>>>(x, W1, dinv, bufA, N);
  // h1 = relu(dinv*(gather+self) + b1)  [fp16, stride 128]
  k_agg<128, 128, 0, h16><<<agrid, 256, 0, stream>>>(bufA, offsets, col, dinv, b1, nullptr, bufB, N, 0);
  // g_scaled = (h1 Wc) * dinv, augmented: col100 = dinv  [fp16, stride 104]
  k_mm<h16, 128, 132, 100, 104, 104, 1><<<mmgrid, 256, 0, stream>>>(bufB, Wc, dinv, bufA, N);
  // three chained S applications (pre-scaled); s-chain rides in cols 100..102
  k_agg<104, 104, 1, h16><<<agrid, 256, 0, stream>>>(bufA, offsets, col, dinv, nullptr, nullptr, bufB, N, 101);
  k_agg<104, 104, 1, h16><<<agrid, 256, 0, stream>>>(bufB, offsets, col, dinv, nullptr, nullptr, bufA, N, 102);
  k_agg<104, 104, 1, h16><<<agrid, 256, 0, stream>>>(bufA, offsets, col, dinv, nullptr, nullptr, bufB, N, -1);
  // final S application + rank-1 bias corrections -> d_out [fp32, 100 wide]
  k_agg<104, 100, 2, float><<<agrid, 256, 0, stream>>>(bufB, offsets, col, dinv, nullptr, corr, (float*)d_out, N, -1);
}